// Round 12
// baseline (24.351 us; speedup 1.0000x reference)
//
#include <hip/hip_runtime.h>
#include <math.h>

#define TAPS 16
#define HALO (TAPS - 1)
#define K2_EPB 256

__device__ __forceinline__ float eluf(float v) { return v > 0.f ? v : expm1f(v); }
__device__ __forceinline__ float dot4(float4 a, float4 b) {
    return a.x * b.x + a.y * b.y + a.z * b.z + a.w * b.w;
}

// Kernel 1: conv1+conv2 for 64 elements/block, 4 lanes per element.
// No LDS, no syncthreads, no halo. Lane role j = t&3; iteration p loads
// float4 #(4p+j): the element's 4 lanes cover one contiguous 64B line ->
// each wave VMEM instr touches exactly 16 full 64B lines.
__global__ __launch_bounds__(256, 8) void NF_conv_kernel(
    const float* __restrict__ x,
    const float* __restrict__ w1, const float* __restrict__ b1,
    const float* __restrict__ w2, const float* __restrict__ b2,
    float2* __restrict__ s, int B)
{
    const int t = threadIdx.x;
    const int j = t & 3;
    const long ge = (long)blockIdx.x * 64 + (t >> 2);

    const float4* xf4 = reinterpret_cast<const float4*>(x);
    const float4* w1v = reinterpret_cast<const float4*>(w1);
    const float4 wv0 = w1v[j];
    const float4 wv1 = w1v[4 + j];

    if (ge >= B) return;

    const float4* base = xf4 + ge * 32;
    float4 v0 = base[j],      v1 = base[4 + j],
           v2 = base[8 + j],  v3 = base[12 + j];
    float a0 = dot4(v0, wv0), a1 = dot4(v1, wv0),
          a2 = dot4(v2, wv0), a3 = dot4(v3, wv0);
    v0 = base[16 + j]; v1 = base[20 + j]; v2 = base[24 + j]; v3 = base[28 + j];
    a0 += dot4(v0, wv1); a1 += dot4(v1, wv1);
    a2 += dot4(v2, wv1); a3 += dot4(v3, wv1);

    // 4-lane butterfly: all 4 lanes end with the full sums
    a0 += __shfl_xor(a0, 1); a1 += __shfl_xor(a1, 1);
    a2 += __shfl_xor(a2, 1); a3 += __shfl_xor(a3, 1);
    a0 += __shfl_xor(a0, 2); a1 += __shfl_xor(a1, 2);
    a2 += __shfl_xor(a2, 2); a3 += __shfl_xor(a3, 2);

    if (j == 0) {
        const float b1s = b1[0];
        float h0 = eluf(a0 + b1s), h1 = eluf(a1 + b1s);
        float h2 = eluf(a2 + b1s), h3 = eluf(a3 + b1s);
        float pr = b2[0] + h0 * w2[0] + h1 * w2[1] + h2 * w2[2] + h3 * w2[3];
        float pi = b2[1] + h0 * w2[4] + h1 * w2[5] + h2 * w2[6] + h3 * w2[7];
        s[ge] = make_float2(eluf(pr), eluf(pi));
    }
}

// Kernel 2: 16-tap complex FIR along the batch axis; halo LOADED from s.
__global__ __launch_bounds__(256) void NF_fir_kernel(
    const float2* __restrict__ s,
    const float* __restrict__ tr, const float* __restrict__ ti,
    float2* __restrict__ out, int B)
{
    __shared__ float s_r[K2_EPB + HALO];
    __shared__ float s_i[K2_EPB + HALO];

    const int t = threadIdx.x;
    const long base = (long)blockIdx.x * K2_EPB;
    const long b = base + t;

    if (t < HALO) {
        long hb = base - HALO + t;
        float2 v = (hb >= 0) ? s[hb] : make_float2(0.f, 0.f);
        s_r[t] = v.x;  s_i[t] = v.y;
    }
    {
        float2 v = (b < B) ? s[b] : make_float2(0.f, 0.f);
        s_r[HALO + t] = v.x;  s_i[HALO + t] = v.y;
    }
    __syncthreads();

    if (b < B) {
        float yr = 0.f, yi = 0.f;
#pragma unroll
        for (int jj = 0; jj < TAPS; ++jj) {
            float a = s_r[HALO + t - jj];
            float c = s_i[HALO + t - jj];
            float trj = tr[jj], tij = ti[jj];
            yr += a * trj - c * tij;
            yi += a * tij + c * trj;
        }
        out[b] = make_float2(yr, yi);
    }
}

extern "C" void kernel_launch(void* const* d_in, const int* in_sizes, int n_in,
                              void* d_out, int out_size, void* d_ws, size_t ws_size,
                              hipStream_t stream) {
    const float* x  = (const float*)d_in[0];
    const float* w1 = (const float*)d_in[1];
    const float* b1 = (const float*)d_in[2];
    const float* w2 = (const float*)d_in[3];
    const float* b2 = (const float*)d_in[4];
    const float* tr = (const float*)d_in[5];
    const float* ti = (const float*)d_in[6];
    float2* out = (float2*)d_out;

    const int B = in_sizes[0] / 128;   // x is (B, 2, 64)
    float2* s = (float2*)d_ws;         // B float2 = 1.6 MB scratch

    const int grid1 = (B + 63) / 64;
    NF_conv_kernel<<<grid1, 256, 0, stream>>>(x, w1, b1, w2, b2, s, B);

    const int grid2 = (B + K2_EPB - 1) / K2_EPB;
    NF_fir_kernel<<<grid2, 256, 0, stream>>>(s, tr, ti, out, B);
}